// Round 22
// baseline (97.609 us; speedup 1.0000x reference)
//
#include <hip/hip_runtime.h>
#include <math.h>

// RankingLoss = mean over rows of sum_{pairs: lab_a-lab_b > TOL} lsig(lg_a-lg_b)
//
// lsig(x) = -ln2*log2(1 + 2^{s_lo - s_hi}),  s = logit*log2e,  E = 2^s.
// Rows bucket-major by label (width TOL). j < C_i => valid, i = high.
// r22: pre FUSED into the work launch with per-row ready flags:
//   blocks 0..63: two-pass LDS bucket reorder for row=bid (r19-proven),
//     export g_labs(lab,s)+g_EC(E,C), threadfence, release-store g_ready[row].
//   blocks 64..959: 2 work items each (side items 0..511 first, then tiles),
//     acquire-spin (s_sleep) on the item's row flag. All 960 blocks are
//     co-resident (launch_bounds(256,4) => >=4 blk/CU => 1024 slots) so the
//     spin cannot deadlock. rank_final resets flags => replays re-sync.
// Work math byte-equivalent to r21 champion (packed v2f tile core, staged
// side windows); only the storage layout (g_EC float2) changed.

#define NN 2048
#define BB 64
#define TOLF 0.01f
#define BLK 256
#define NTILE 20                         // i-tiles of 512: offsets it*(it+1)
#define TILEBLKS (BB * NTILE)            // 1280
#define SIDEBLKS (BB * 8)                // 512
#define NITEMS (TILEBLKS + SIDEBLKS)     // 1792
#define WBLKS (NITEMS / 2)               // 896 work blocks, 2 items each
#define GRID (BB + WBLKS)                // 960
#define SWIN 448
#define LOG2E 1.4426950408889634f

typedef float v2f __attribute__((ext_vector_type(2)));

__device__ float2 g_labs[BB][NN];   // (label, s) bucket-major
__device__ float2 g_EC[BB][NN];     // (E = 2^s, C-as-int-bits)
__device__ int    g_ready[BB * 16]; // padded flags (64B apart); BSS zero-init
__device__ float  g_part[TILEBLKS];
__device__ double g_partS[SIDEBLKS];

#define SMEM_BYTES 17664

__global__ __launch_bounds__(BLK, 4) void rank_fused(const float* __restrict__ logits,
                                                     const float* __restrict__ labels) {
    __shared__ __align__(16) char smem[SMEM_BYTES];
    const int bid = blockIdx.x, tid = threadIdx.x;

    if (bid < BB) {
        // ---------------- producer: bucket reorder for one row ----------------
        float2* st = (float2*)smem;                  // [2048] 16 KB
        int* cnt  = (int*)(smem + 16384);            // [100]
        int* offs = cnt + 100;                       // [100]
        int* pref = offs + 100;                      // [101]
        int* wtot = pref + 101;
        const int row = bid;
        const float* lg = logits + (size_t)row * NN;
        const float* lb = labels + (size_t)row * NN;

        for (int x = tid; x < 100; x += BLK) { cnt[x] = 0; offs[x] = 0; }
        __syncthreads();
        float la8[8], lg8[8];
        int   p8[8];
#pragma unroll
        for (int q = 0; q < 8; ++q) {
            int x = tid + q * BLK;
            la8[q] = lb[x];
            lg8[q] = lg[x];
            atomicAdd(&cnt[min(99, (int)(la8[q] * 100.0f))], 1);
        }
        __syncthreads();
        {   // wave-parallel exclusive prefix over 100 counts (waves 0-1)
            int v = (tid < 100) ? cnt[tid] : 0;
            int x = v;
#pragma unroll
            for (int o = 1; o < 64; o <<= 1) {
                int y = __shfl_up(x, o);
                if ((tid & 63) >= o) x += y;
            }
            if (tid == 63) *wtot = x;
            __syncthreads();
            if (tid >= 64 && tid < 128) x += *wtot;
            if (tid < 101) pref[tid] = x - v;
        }
        __syncthreads();
        // pass A: scatter (lab, s); export g_labs
#pragma unroll
        for (int q = 0; q < 8; ++q) {
            int b = min(99, (int)(la8[q] * 100.0f));
            p8[q] = pref[b] + atomicAdd(&offs[b], 1);
            st[p8[q]] = make_float2(la8[q], lg8[q] * LOG2E);
        }
        __syncthreads();
        for (int x = tid; x < NN; x += BLK) g_labs[row][x] = st[x];
        __syncthreads();
        // pass B: scatter (E, C-bits); export g_EC
#pragma unroll
        for (int q = 0; q < 8; ++q) {
            int b = min(99, (int)(la8[q] * 100.0f));
            float s = lg8[q] * LOG2E;
            st[p8[q]] = make_float2(__builtin_amdgcn_exp2f(s),
                                    __int_as_float((b >= 1) ? pref[b - 1] : 0));
        }
        __syncthreads();
        for (int x = tid; x < NN; x += BLK) g_EC[row][x] = st[x];

        __threadfence();
        if (tid == 0)
            __hip_atomic_store(&g_ready[row * 16], 1, __ATOMIC_RELEASE,
                               __HIP_MEMORY_SCOPE_AGENT);
        return;
    }

    // ---------------- consumer: two work items per block ----------------
    const int wb = bid - BB;
    for (int pass = 0; pass < 2; ++pass) {
        const int item = wb + pass * WBLKS;
        const int row = (item < SIDEBLKS) ? (item >> 3)
                                          : ((item - SIDEBLKS) / NTILE);
        // wait for this row's data
        if (tid == 0) {
            while (__hip_atomic_load(&g_ready[row * 16], __ATOMIC_ACQUIRE,
                                     __HIP_MEMORY_SCOPE_AGENT) == 0)
                __builtin_amdgcn_s_sleep(8);
        }
        __syncthreads();

        if (item < SIDEBLKS) {
            // ---- side: bucket-distance <= 1 pairs, window staged in LDS ----
            float2* sLS = (float2*)smem;             // [448]
            float*  sE  = (float*)(smem + 3584);     // [448]
            int*    sCs = (int*)(smem + 5376);
            double* sdw = (double*)(smem + 5384);    // [4]
            const int c0 = (item & 7) << 8;
            if (tid == 0) *sCs = __float_as_int(g_EC[row][c0].y);
            __syncthreads();
            const int Cs  = *sCs;
            const int len = c0 + 256 - Cs;
            for (int x = tid; x < len; x += BLK) {
                sLS[x] = g_labs[row][Cs + x];
                sE[x]  = g_EC[row][Cs + x].x;
            }
            __syncthreads();

            const int i    = c0 + tid;
            const int iloc = i - Cs;
            const float2 lsi = sLS[iloc];
            const float lai = lsi.x, si = lsi.y;
            const float2 eci = g_EC[row][i];
            const float Ei  = eci.x;
            const int wloc  = __float_as_int(eci.y) - Cs;

            float accL = 0.0f, accS = 0.0f;
            float p = 1.0f;
            int cnt8 = 0;
            for (int j = wloc; j < iloc; ++j) {
                float2 ls = sLS[j];
                float ld = lai - ls.x;
                bool valid = fabsf(ld) > TOLF;       // exact reference predicate
                float term = valid ? (Ei + sE[j]) : 1.0f;
                p *= term;
                if (++cnt8 == 8) { accL += __builtin_amdgcn_logf(p); p = 1.0f; cnt8 = 0; }
                float sh = (ld > 0.0f) ? si : ls.y;
                accS -= valid ? sh : 0.0f;
            }
            accL += __builtin_amdgcn_logf(p);

            double acc = (double)accL + (double)accS;
            for (int off = 32; off > 0; off >>= 1) acc += __shfl_down(acc, off);
            if ((tid & 63) == 0) sdw[tid >> 6] = acc;
            __syncthreads();
            if (tid == 0) g_partS[item] = sdw[0] + sdw[1] + sdw[2] + sdw[3];
            __syncthreads();                         // smem reuse fence
        } else {
            // ---- tile: packed mask-free core (r21 champion) ----
            float* swin  = (float*)smem;             // [256]
            float* swave = (float*)(smem + 1024);    // [4]
            const int tb = item - SIDEBLKS;
            const int t = tb % NTILE;
            const int it = (t < 2) ? 0 : (t < 6) ? 1 : (t < 12) ? 2 : 3;
            const int jt = t - it * (it + 1);
            const int ibeg = it * 512, jbeg = jt * 256;

            float accL = 0.0f;
            const int Cmax = __float_as_int(g_EC[row][ibeg + 511].y);
            if (jbeg < Cmax) {
                swin[tid] = g_EC[row][jbeg + tid].x;
                __syncthreads();
                const int ia = ibeg + tid;
                const int ib = ia + 256;
                const float2 eca = g_EC[row][ia];
                const float2 ecb = g_EC[row][ib];
                const float invEa = __builtin_amdgcn_rcpf(eca.x);
                const float invEb = __builtin_amdgcn_rcpf(ecb.x);
                v2f iA; iA.x = invEa; iA.y = invEa;
                v2f iB; iB.x = invEb; iB.y = invEb;
                int tripa = max(0, min(256, __float_as_int(eca.y) - jbeg));
                int tripb = max(0, min(256, __float_as_int(ecb.y) - jbeg));
                const int m16a = tripa & ~15;
                const int m16b = tripb & ~15;

                for (int jj = 0; jj < m16a; jj += 16) {
                    const v2f* qw = (const v2f*)&swin[jj];   // uniform b64 bcast
                    v2f a0; a0.x = 1.0f; a0.y = 1.0f;
                    v2f a1 = a0, b0 = a0, b1 = a0;
#pragma unroll
                    for (int u = 0; u < 4; ++u) {
                        v2f w = qw[u];
                        a0 = __builtin_elementwise_fma(w * iA, a0, a0);
                        b0 = __builtin_elementwise_fma(w * iB, b0, b0);
                    }
#pragma unroll
                    for (int u = 4; u < 8; ++u) {
                        v2f w = qw[u];
                        a1 = __builtin_elementwise_fma(w * iA, a1, a1);
                        b1 = __builtin_elementwise_fma(w * iB, b1, b1);
                    }
                    accL += __builtin_amdgcn_logf(a0.x * a0.y)
                          + __builtin_amdgcn_logf(a1.x * a1.y)
                          + __builtin_amdgcn_logf(b0.x * b0.y)
                          + __builtin_amdgcn_logf(b1.x * b1.y);
                }
                for (int jj = m16a; jj < m16b; jj += 16) {
                    const v2f* qw = (const v2f*)&swin[jj];
                    v2f b0; b0.x = 1.0f; b0.y = 1.0f;
                    v2f b1 = b0;
#pragma unroll
                    for (int u = 0; u < 4; ++u)
                        b0 = __builtin_elementwise_fma(qw[u] * iB, b0, b0);
#pragma unroll
                    for (int u = 4; u < 8; ++u)
                        b1 = __builtin_elementwise_fma(qw[u] * iB, b1, b1);
                    accL += __builtin_amdgcn_logf(b0.x * b0.y)
                          + __builtin_amdgcn_logf(b1.x * b1.y);
                }
                if (m16a < tripa) {
                    float p0 = 1.0f, p1 = 1.0f;
#pragma unroll
                    for (int u = 0; u < 8; ++u) {
                        float t0 = (m16a + u     < tripa) ? fmaf(swin[m16a + u],     invEa, 1.0f) : 1.0f;
                        float t1 = (m16a + 8 + u < tripa) ? fmaf(swin[m16a + 8 + u], invEa, 1.0f) : 1.0f;
                        p0 *= t0; p1 *= t1;
                    }
                    accL += __builtin_amdgcn_logf(p0) + __builtin_amdgcn_logf(p1);
                }
                if (m16b < tripb) {
                    float p0 = 1.0f, p1 = 1.0f;
#pragma unroll
                    for (int u = 0; u < 8; ++u) {
                        float t0 = (m16b + u     < tripb) ? fmaf(swin[m16b + u],     invEb, 1.0f) : 1.0f;
                        float t1 = (m16b + 8 + u < tripb) ? fmaf(swin[m16b + 8 + u], invEb, 1.0f) : 1.0f;
                        p0 *= t0; p1 *= t1;
                    }
                    accL += __builtin_amdgcn_logf(p0) + __builtin_amdgcn_logf(p1);
                }
            }
            for (int off = 32; off > 0; off >>= 1) accL += __shfl_down(accL, off);
            if ((tid & 63) == 0) swave[tid >> 6] = accL;
            __syncthreads();
            if (tid == 0) g_part[tb] = swave[0] + swave[1] + swave[2] + swave[3];
            __syncthreads();                         // smem reuse fence
        }
    }
}

__global__ __launch_bounds__(BLK) void rank_final(float* __restrict__ out) {
    double acc = 0.0;
    for (int idx = threadIdx.x; idx < TILEBLKS; idx += BLK) acc += (double)g_part[idx];
    for (int idx = threadIdx.x; idx < SIDEBLKS; idx += BLK) acc += g_partS[idx];
    for (int off = 32; off > 0; off >>= 1) acc += __shfl_down(acc, off);
    __shared__ double sw[4];
    if ((threadIdx.x & 63) == 0) sw[threadIdx.x >> 6] = acc;
    __syncthreads();
    if (threadIdx.x == 0)
        out[0] = (float)((sw[0] + sw[1] + sw[2] + sw[3]) *
                         (-0.6931471805599453 / (double)BB));
    if (threadIdx.x < BB) g_ready[threadIdx.x * 16] = 0;   // re-arm for next launch
}

extern "C" void kernel_launch(void* const* d_in, const int* in_sizes, int n_in,
                              void* d_out, int out_size, void* d_ws, size_t ws_size,
                              hipStream_t stream) {
    const float* logits = (const float*)d_in[0];
    const float* labels = (const float*)d_in[1];
    float* out = (float*)d_out;
    (void)in_sizes; (void)n_in; (void)out_size; (void)d_ws; (void)ws_size;

    rank_fused<<<GRID, BLK, 0, stream>>>(logits, labels);
    rank_final<<<1, BLK, 0, stream>>>(out);
}

// Round 23
// 28.534 us; speedup vs baseline: 3.4208x; 3.4208x over previous
//
#include <hip/hip_runtime.h>
#include <math.h>

// RankingLoss = mean over rows of sum_{pairs: lab_a-lab_b > TOL} lsig(lg_a-lg_b)
//
// lsig(x) = -ln2*log2(1 + 2^{s_lo - s_hi}),  s = logit*log2e,  E = 2^s.
// Rows bucket-major by label (width TOL). j < C_i (C_i = start of bucket
// b_i-1) => pair valid, i = high.
//   tile core (packed v2f, r21): t = E_j*invE_i; p = fma(t,p,p); 512i x 256j.
//   side (C_i <= j < i): exact |ld|>TOL mask; (Ei+Ej) product; accS -= s_hi.
// r23 change (single variable vs r21 champion 26.6us): rank_pre is now
// 512 BLOCKS (8 per row, one per 256-elem slice). Each block redundantly
// histograms the full row from LDS (labels 8KB, L2-shared), wave-scans
// totals -> pref, derives its slice's exact per-bucket base
// (pref[b] + sum_{s'<slice} hist[s'][b]), scatters only its 256 elements.
// No cross-block comm, no global atomics. Old pre: 64 blocks, 1/CU,
// latency-bound dependent passes — the last unexonerated ~12us candidate.

#define NN 2048
#define BB 64
#define TOLF 0.01f
#define BLK 256
#define NTILE 20                         // i-tiles of 512: offsets it*(it+1)
#define TILEBLKS (BB * NTILE)            // 1280
#define SIDEBLKS (BB * 8)                // 512
#define WGRID (TILEBLKS + SIDEBLKS)      // 1792
#define PREBLKS (BB * 8)                 // 512
#define SWIN 448
#define LOG2E 1.4426950408889634f

typedef float v2f __attribute__((ext_vector_type(2)));

__device__ float2 g_labs[BB][NN];  // (label, s) bucket-major
__device__ float  g_Es[BB][NN];    // 2^s = e^logit
__device__ int    g_C[BB][NN];     // start of bucket b_i - 1
__device__ float  g_part[TILEBLKS];
__device__ double g_partS[SIDEBLKS];

// ------- pre: 8 blocks/row, redundant hist, exact slice bases, scatter -------
__global__ __launch_bounds__(BLK) void rank_pre(const float* __restrict__ logits,
                                                const float* __restrict__ labels) {
    __shared__ float sLab[NN];           // 8 KB full label row
    __shared__ int   hist[8][100];
    __shared__ int   tot[100], before[100];
    __shared__ int   pref[101], cursor[100];
    __shared__ int   wtot;
    const int bid = blockIdx.x;
    const int row = bid >> 3;
    const int slice = bid & 7;
    const int tid = threadIdx.x;
    const float* lg = logits + (size_t)row * NN;
    const float* lb = labels + (size_t)row * NN;

    for (int x = tid; x < 800; x += BLK) ((int*)hist)[x] = 0;
    __syncthreads();
#pragma unroll
    for (int q = 0; q < 8; ++q) {        // load full row + per-slice histograms
        int x = q * BLK + tid;
        float la = lb[x];
        sLab[x] = la;
        atomicAdd(&hist[q][min(99, (int)(la * 100.0f))], 1);   // x>>8 == q
    }
    __syncthreads();
    if (tid < 100) {                     // totals + count in earlier slices
        int run = 0, bef = 0;
#pragma unroll
        for (int s = 0; s < 8; ++s) { if (s == slice) bef = run; run += hist[s][tid]; }
        tot[tid] = run;
        before[tid] = bef;
    }
    __syncthreads();
    {   // wave-parallel exclusive prefix over 100 totals (waves 0-1)
        int v = (tid < 100) ? tot[tid] : 0;
        int x = v;
#pragma unroll
        for (int o = 1; o < 64; o <<= 1) {
            int y = __shfl_up(x, o);
            if ((tid & 63) >= o) x += y;
        }
        if (tid == 63) wtot = x;
        __syncthreads();
        if (tid >= 64 && tid < 128) x += wtot;
        if (tid < 101) pref[tid] = x - v;
    }
    __syncthreads();
    if (tid < 100) cursor[tid] = pref[tid] + before[tid];
    __syncthreads();
    {   // place own slice's 256 elements (exact global bucket ranks)
        int x = (slice << 8) + tid;
        float la  = sLab[x];
        float lgx = lg[x];
        int b = min(99, (int)(la * 100.0f));
        int p = atomicAdd(&cursor[b], 1);
        float s = lgx * LOG2E;
        g_labs[row][p] = make_float2(la, s);
        g_Es[row][p]   = __builtin_amdgcn_exp2f(s);
        g_C[row][p]    = (b >= 1) ? pref[b - 1] : 0;
    }
}

// ---------------- main work: side (LDS-staged, first) + tiles (r21) ----------------
__global__ __launch_bounds__(BLK) void rank_work() {
    const int bid = blockIdx.x;
    if (bid < SIDEBLKS) {
        __shared__ float2 sLS[SWIN];
        __shared__ float  sE[SWIN];
        __shared__ int    sCs;
        __shared__ double sdw[4];
        const int row = bid >> 3;
        const int c0  = (bid & 7) << 8;
        const int tid = threadIdx.x;
        if (tid == 0) sCs = g_C[row][c0];
        __syncthreads();
        const int Cs  = sCs;
        const int len = c0 + 256 - Cs;
        for (int x = tid; x < len; x += BLK) {
            sLS[x] = g_labs[row][Cs + x];
            sE[x]  = g_Es[row][Cs + x];
        }
        __syncthreads();

        const int i    = c0 + tid;
        const int iloc = i - Cs;
        const float2 lsi = sLS[iloc];
        const float lai = lsi.x, si = lsi.y;
        const float Ei  = sE[iloc];
        const int wloc  = g_C[row][i] - Cs;

        float accL = 0.0f, accS = 0.0f;
        float p = 1.0f;
        int cnt8 = 0;
        for (int j = wloc; j < iloc; ++j) {
            float2 ls = sLS[j];
            float ld = lai - ls.x;
            bool valid = fabsf(ld) > TOLF;         // exact reference predicate
            float term = valid ? (Ei + sE[j]) : 1.0f;
            p *= term;
            if (++cnt8 == 8) { accL += __builtin_amdgcn_logf(p); p = 1.0f; cnt8 = 0; }
            float sh = (ld > 0.0f) ? si : ls.y;
            accS -= valid ? sh : 0.0f;
        }
        accL += __builtin_amdgcn_logf(p);

        double acc = (double)accL + (double)accS;
        for (int off = 32; off > 0; off >>= 1) acc += __shfl_down(acc, off);
        if ((tid & 63) == 0) sdw[tid >> 6] = acc;
        __syncthreads();
        if (tid == 0) g_partS[bid] = sdw[0] + sdw[1] + sdw[2] + sdw[3];
    } else {
        __shared__ __align__(16) float swin[256];
        __shared__ float swave[4];
        const int tb = bid - SIDEBLKS;
        const int row = tb / NTILE;                // block-uniform
        const int t = tb % NTILE;
        const int it = (t < 2) ? 0 : (t < 6) ? 1 : (t < 12) ? 2 : 3;
        const int jt = t - it * (it + 1);
        const int ibeg = it * 512, jbeg = jt * 256;

        float accL = 0.0f;
        const int Cmax = g_C[row][ibeg + 511];     // C monotone in position
        if (jbeg < Cmax) {
            for (int x = threadIdx.x; x < 64; x += BLK)
                ((float4*)swin)[x] = ((const float4*)&g_Es[row][jbeg])[x];
            __syncthreads();
            const int ia = ibeg + threadIdx.x;
            const int ib = ia + 256;
            const float invEa = __builtin_amdgcn_rcpf(g_Es[row][ia]);
            const float invEb = __builtin_amdgcn_rcpf(g_Es[row][ib]);
            v2f iA; iA.x = invEa; iA.y = invEa;
            v2f iB; iB.x = invEb; iB.y = invEb;
            int tripa = max(0, min(256, g_C[row][ia] - jbeg));
            int tripb = max(0, min(256, g_C[row][ib] - jbeg));   // >= tripa
            const int m16a = tripa & ~15;
            const int m16b = tripb & ~15;

            for (int jj = 0; jj < m16a; jj += 16) {
                const v2f* qw = (const v2f*)&swin[jj];   // uniform: b64 broadcast
                v2f a0; a0.x = 1.0f; a0.y = 1.0f;
                v2f a1 = a0, b0 = a0, b1 = a0;
#pragma unroll
                for (int u = 0; u < 4; ++u) {
                    v2f w = qw[u];
                    a0 = __builtin_elementwise_fma(w * iA, a0, a0);
                    b0 = __builtin_elementwise_fma(w * iB, b0, b0);
                }
#pragma unroll
                for (int u = 4; u < 8; ++u) {
                    v2f w = qw[u];
                    a1 = __builtin_elementwise_fma(w * iA, a1, a1);
                    b1 = __builtin_elementwise_fma(w * iB, b1, b1);
                }
                accL += __builtin_amdgcn_logf(a0.x * a0.y)
                      + __builtin_amdgcn_logf(a1.x * a1.y)
                      + __builtin_amdgcn_logf(b0.x * b0.y)
                      + __builtin_amdgcn_logf(b1.x * b1.y);
            }
            for (int jj = m16a; jj < m16b; jj += 16) {
                const v2f* qw = (const v2f*)&swin[jj];
                v2f b0; b0.x = 1.0f; b0.y = 1.0f;
                v2f b1 = b0;
#pragma unroll
                for (int u = 0; u < 4; ++u)
                    b0 = __builtin_elementwise_fma(qw[u] * iB, b0, b0);
#pragma unroll
                for (int u = 4; u < 8; ++u)
                    b1 = __builtin_elementwise_fma(qw[u] * iB, b1, b1);
                accL += __builtin_amdgcn_logf(b0.x * b0.y)
                      + __builtin_amdgcn_logf(b1.x * b1.y);
            }
            if (m16a < tripa) {
                float p0 = 1.0f, p1 = 1.0f;
#pragma unroll
                for (int u = 0; u < 8; ++u) {
                    float t0 = (m16a + u     < tripa) ? fmaf(swin[m16a + u],     invEa, 1.0f) : 1.0f;
                    float t1 = (m16a + 8 + u < tripa) ? fmaf(swin[m16a + 8 + u], invEa, 1.0f) : 1.0f;
                    p0 *= t0; p1 *= t1;
                }
                accL += __builtin_amdgcn_logf(p0) + __builtin_amdgcn_logf(p1);
            }
            if (m16b < tripb) {
                float p0 = 1.0f, p1 = 1.0f;
#pragma unroll
                for (int u = 0; u < 8; ++u) {
                    float t0 = (m16b + u     < tripb) ? fmaf(swin[m16b + u],     invEb, 1.0f) : 1.0f;
                    float t1 = (m16b + 8 + u < tripb) ? fmaf(swin[m16b + 8 + u], invEb, 1.0f) : 1.0f;
                    p0 *= t0; p1 *= t1;
                }
                accL += __builtin_amdgcn_logf(p0) + __builtin_amdgcn_logf(p1);
            }
        }
        for (int off = 32; off > 0; off >>= 1) accL += __shfl_down(accL, off);
        if ((threadIdx.x & 63) == 0) swave[threadIdx.x >> 6] = accL;
        __syncthreads();
        if (threadIdx.x == 0)
            g_part[tb] = swave[0] + swave[1] + swave[2] + swave[3];
    }
}

__global__ __launch_bounds__(BLK) void rank_final(float* __restrict__ out) {
    double acc = 0.0;
    for (int idx = threadIdx.x; idx < TILEBLKS; idx += BLK) acc += (double)g_part[idx];
    for (int idx = threadIdx.x; idx < SIDEBLKS; idx += BLK) acc += g_partS[idx];
    for (int off = 32; off > 0; off >>= 1) acc += __shfl_down(acc, off);
    __shared__ double sw[4];
    if ((threadIdx.x & 63) == 0) sw[threadIdx.x >> 6] = acc;
    __syncthreads();
    if (threadIdx.x == 0)
        out[0] = (float)((sw[0] + sw[1] + sw[2] + sw[3]) *
                         (-0.6931471805599453 / (double)BB));
}

extern "C" void kernel_launch(void* const* d_in, const int* in_sizes, int n_in,
                              void* d_out, int out_size, void* d_ws, size_t ws_size,
                              hipStream_t stream) {
    const float* logits = (const float*)d_in[0];
    const float* labels = (const float*)d_in[1];
    float* out = (float*)d_out;
    (void)in_sizes; (void)n_in; (void)out_size; (void)d_ws; (void)ws_size;

    rank_pre<<<PREBLKS, BLK, 0, stream>>>(logits, labels);
    rank_work<<<WGRID, BLK, 0, stream>>>();
    rank_final<<<1, BLK, 0, stream>>>(out);
}